// Round 3
// baseline (96.495 us; speedup 1.0000x reference)
//
#include <hip/hip_runtime.h>

// ConvCapsules2d: V[b,i,c,d,f,g,k,l] = (sum_p poses[b,i,p,2f+k,2g+l]) * W[i,c,d,k,l]
// poses (16,32,16,14,14) f32, W (32,32,16,3,3) f32
// out (16,32,32,16,6,6,3,3) f32 = 84,934,656 elems = 339.7 MB -> HBM-write-bound.
//
// R3 structure: each thread owns a FIXED float4 slot q of the 324-float
// (f,g,k,l) panel; s-quad lives in registers; loop over the 128 (c,d)
// panels does only 4 broadcast w-reads + 4 muls + 1 NT store.
// 243 active threads/block write 4*tid within a 972-float group ->
// block store stream is fully contiguous.

#define N_BATCH 16
#define B_IN    32
#define P_DIM   16
#define H_IN    14
#define C_OUT   32
#define D_OUT   16
#define S_ELEMS 324                 // 6*6*3*3 panel
#define CQ      8                   // c's per block
#define NCD     (CQ * D_OUT)        // 128 (c,d) panels per block
#define W_ELEMS (NCD * 9)           // 1152 contiguous floats of W

typedef float f32x4 __attribute__((ext_vector_type(4)));

__global__ __launch_bounds__(256)
void convcaps_kernel(const float* __restrict__ poses,
                     const float* __restrict__ W,
                     float* __restrict__ out)
{
    __shared__ float s_lds[S_ELEMS];
    __shared__ float w_lds[W_ELEMS];

    const int tid = threadIdx.x;
    const int blk = blockIdx.x;        // 0..2047
    const int cq  = blk & 3;
    const int bi  = blk >> 2;
    const int i   = bi & (B_IN - 1);
    const int b   = bi >> 5;
    const int c0  = cq * CQ;

    // ---- stage 1: s[e] = sum_p poses[b,i,p,2f+k,2g+l], e = ((f*6+g)*3+k)*3+l
    for (int e = tid; e < S_ELEMS; e += 256) {
        int f  = e / 54;
        int r  = e - f * 54;
        int g  = r / 9;
        int kl = r - g * 9;
        int k  = kl / 3;
        int l  = kl - k * 3;
        const float* p0 = poses
            + (size_t)(b * B_IN + i) * (P_DIM * H_IN * H_IN)
            + (2 * f + k) * H_IN + (2 * g + l);
        float acc = 0.f;
        #pragma unroll
        for (int p = 0; p < P_DIM; ++p) acc += p0[p * (H_IN * H_IN)];
        s_lds[e] = acc;
    }

    // ---- stage 2: W[i, c0..c0+7, :, :, :] contiguous 1152 floats
    {
        const float* wsrc = W + (size_t)(i * C_OUT + c0) * (D_OUT * 9);
        for (int j = tid; j < W_ELEMS; j += 256) w_lds[j] = wsrc[j];
    }
    __syncthreads();

    // ---- stage 3: 243 active threads; thread = (rep, q), q = fixed float4 slot
    if (tid < 243) {
        const int q   = tid % 81;
        const int rep = tid / 81;           // 0..2
        const int e0  = q * 4;

        // s-quad once into registers (16B-aligned LDS read)
        const f32x4 s4 = *(const f32x4*)&s_lds[e0];

        int kl0 = e0 % 9;
        int kl1 = kl0 + 1; kl1 = (kl1 == 9) ? 0 : kl1;
        int kl2 = kl1 + 1; kl2 = (kl2 == 9) ? 0 : kl2;
        int kl3 = kl2 + 1; kl3 = (kl3 == 9) ? 0 : kl3;

        float* optr = out
            + (size_t)((b * B_IN + i) * C_OUT + c0) * (D_OUT * S_ELEMS)
            + rep * S_ELEMS + e0;
        const float* wrow = &w_lds[rep * 9];

        // cd = rep, rep+3, ... ; each iteration: 4 broadcast LDS reads,
        // 4 muls, one 16B NT store. Block-wide stores are contiguous.
        #pragma unroll 4
        for (int cd = rep; cd < NCD; cd += 3) {
            f32x4 v;
            v.x = s4.x * wrow[kl0];
            v.y = s4.y * wrow[kl1];
            v.z = s4.z * wrow[kl2];
            v.w = s4.w * wrow[kl3];
            __builtin_nontemporal_store(v, (f32x4*)optr);
            optr += 3 * S_ELEMS;
            wrow += 27;
        }
    }
}

extern "C" void kernel_launch(void* const* d_in, const int* in_sizes, int n_in,
                              void* d_out, int out_size, void* d_ws, size_t ws_size,
                              hipStream_t stream) {
    const float* poses = (const float*)d_in[0];
    const float* W     = (const float*)d_in[1];
    float* out         = (float*)d_out;

    const int grid = N_BATCH * B_IN * (C_OUT / CQ);   // 2048
    convcaps_kernel<<<grid, 256, 0, stream>>>(poses, W, out);
}

// Round 4
// 72.954 us; speedup vs baseline: 1.3227x; 1.3227x over previous
//
#include <hip/hip_runtime.h>

// ConvCapsules2d: V[b,i,c,d,f,g,k,l] = (sum_p poses[b,i,p,2f+k,2g+l]) * W[i,c,d,k,l]
// poses (16,32,16,14,14) f32, W (32,32,16,3,3) f32
// out (16,32,32,16,6,6,3,3) f32 = 84,934,656 elems = 339.7 MB -> HBM-write-bound.
//
// R4 = R2 structure (76.3 us) with ONE change: regular stores instead of
// nontemporal (A/B test: fill kernel hits 6.9 TB/s with regular stores).

#define N_BATCH 16
#define B_IN    32
#define P_DIM   16
#define H_IN    14
#define C_OUT   32
#define D_OUT   16
#define KSZ     3

typedef float f32x4 __attribute__((ext_vector_type(4)));

#define S_ELEMS 324                              // 6*6*3*3 panel
#define CQ      8                                // c's per block
#define W_ELEMS (CQ * D_OUT * KSZ * KSZ)         // 1152
#define V4_PER_BLOCK (CQ * D_OUT * (S_ELEMS/4))  // 10368

__global__ __launch_bounds__(256)
void convcaps_kernel(const float* __restrict__ poses,
                     const float* __restrict__ W,
                     float* __restrict__ out)
{
    __shared__ float s_lds[S_ELEMS];
    __shared__ float w_lds[W_ELEMS];

    const int tid = threadIdx.x;
    const int blk = blockIdx.x;        // 0 .. 2047
    const int cq  = blk & 3;
    const int bi  = blk >> 2;
    const int i   = bi & (B_IN - 1);
    const int b   = bi >> 5;
    const int c0  = cq * CQ;

    // ---- stage 1: s[e] = sum_p poses[b,i,p,2f+k,2g+l], e = ((f*6+g)*3+k)*3+l
    for (int e = tid; e < S_ELEMS; e += 256) {
        int f  = e / 54;
        int r  = e - f * 54;
        int g  = r / 9;
        int kl = r - g * 9;
        int k  = kl / 3;
        int l  = kl - k * 3;
        const float* p0 = poses
            + (size_t)(b * B_IN + i) * (P_DIM * H_IN * H_IN)
            + (2 * f + k) * H_IN + (2 * g + l);
        float acc = 0.f;
        #pragma unroll
        for (int p = 0; p < P_DIM; ++p) acc += p0[p * (H_IN * H_IN)];
        s_lds[e] = acc;
    }

    // ---- stage 2: W[i, c0..c0+7, :, :, :] contiguous 1152 floats
    {
        const float* wsrc = W + (size_t)(i * C_OUT + c0) * (D_OUT * 9);
        for (int j = tid; j < W_ELEMS; j += 256) w_lds[j] = wsrc[j];
    }
    __syncthreads();

    // ---- stage 3: 8*16*324 floats, coalesced float4 stores (regular, not NT)
    float* obase = out + (size_t)((b * B_IN + i) * C_OUT + c0) * (D_OUT * S_ELEMS);

    for (int idx = tid; idx < V4_PER_BLOCK; idx += 256) {
        int cd = idx / 81;
        int q  = idx - cd * 81;
        int e  = q * 4;

        const float* wrow = &w_lds[cd * 9];
        f32x4 v;
        {
            int kl0 = (e + 0) % 9;
            int kl1 = (e + 1) % 9;
            int kl2 = (e + 2) % 9;
            int kl3 = (e + 3) % 9;
            v.x = s_lds[e + 0] * wrow[kl0];
            v.y = s_lds[e + 1] * wrow[kl1];
            v.z = s_lds[e + 2] * wrow[kl2];
            v.w = s_lds[e + 3] * wrow[kl3];
        }
        *(f32x4*)(obase + (size_t)cd * S_ELEMS + e) = v;
    }
}

extern "C" void kernel_launch(void* const* d_in, const int* in_sizes, int n_in,
                              void* d_out, int out_size, void* d_ws, size_t ws_size,
                              hipStream_t stream) {
    const float* poses = (const float*)d_in[0];
    const float* W     = (const float*)d_in[1];
    float* out         = (float*)d_out;

    const int grid = N_BATCH * B_IN * (C_OUT / CQ);   // 2048
    convcaps_kernel<<<grid, 256, 0, stream>>>(poses, W, out);
}